// Round 3
// baseline (368.033 us; speedup 1.0000x reference)
//
#include <hip/hip_runtime.h>
#include <stdint.h>

#define NTAGS 256
#define BATCH 64
#define SEQ   512
#define MB    16          // batches per workgroup (the mfma N dimension)
#define NTHREADS 256      // 4 waves; wave w owns tag' range [64w, 64w+64)

typedef __attribute__((ext_vector_type(8))) short short8;   // 8 bf16 (4 VGPRs)
typedef __attribute__((ext_vector_type(4))) float f32x4;

__device__ __forceinline__ unsigned int f32_to_bf16_bits(float f) {
  unsigned int u = __float_as_uint(f);
  return (u + 0x7FFFu + ((u >> 16) & 1u)) >> 16;
}
__device__ __forceinline__ float wave_sum(float v) {
#pragma unroll
  for (int o = 32; o; o >>= 1) v += __shfl_xor(v, o);
  return v;
}

#define LOG2E 1.4426950408889634f

// One mfma sweep: D[tag',batch] += E' * alpha, 8 K-chunks, 4 M-tiles (acc0..3).
// B-frag: lane (p=l&15 batch-col, q=l>>4): alpha[tags 32c+8q..+7, p] = contiguous
// b128 in LDS (XOR-swizzled). A-frag aF[i][c] holds E' with the SAME (q,j)->tag
// mapping, so the result is invariant to the hardware's internal k-permutation.
#define MFMA_ALL(RB) \
    f32x4 acc0 = {0.f,0.f,0.f,0.f}, acc1 = {0.f,0.f,0.f,0.f}, \
          acc2 = {0.f,0.f,0.f,0.f}, acc3 = {0.f,0.f,0.f,0.f}; \
    _Pragma("unroll") \
    for (int c = 0; c < 8; ++c) { \
      const short8 bf = *(const short8*)&alds[RB][bidxs[c]]; \
      acc0 = __builtin_amdgcn_mfma_f32_16x16x32_bf16(aF[0][c], bf, acc0, 0, 0, 0); \
      acc1 = __builtin_amdgcn_mfma_f32_16x16x32_bf16(aF[1][c], bf, acc1, 0, 0, 0); \
      acc2 = __builtin_amdgcn_mfma_f32_16x16x32_bf16(aF[2][c], bf, acc2, 0, 0, 0); \
      acc3 = __builtin_amdgcn_mfma_f32_16x16x32_bf16(aF[3][c], bf, acc3, 0, 0, 0); \
    }

// Forward epilogue, one M-tile: C/D layout (verified m89): lane holds col=p,
// rows tag' = 64*wid+16*I+4*q+r. new = m ? dot*exp2(g*log2e - e) : old*2^-e.
#define EPI_TILE_F(I, ACCI, GB, WB) { \
      const f32x4 g4 = GB[I]; \
      const float n0 = MM ? ACCI[0] * exp2f(fmaf(g4[0], LOG2E, -ef)) : sOld[I][0] * sc; \
      const float n1 = MM ? ACCI[1] * exp2f(fmaf(g4[1], LOG2E, -ef)) : sOld[I][1] * sc; \
      const float n2 = MM ? ACCI[2] * exp2f(fmaf(g4[2], LOG2E, -ef)) : sOld[I][2] * sc; \
      const float n3 = MM ? ACCI[3] * exp2f(fmaf(g4[3], LOG2E, -ef)) : sOld[I][3] * sc; \
      sOld[I][0] = n0; sOld[I][1] = n1; sOld[I][2] = n2; sOld[I][3] = n3; \
      mxl = fmaxf(mxl, fmaxf(fmaxf(n0, n1), fmaxf(n2, n3))); \
      uint2 wv; \
      wv.x = f32_to_bf16_bits(n0) | (f32_to_bf16_bits(n1) << 16); \
      wv.y = f32_to_bf16_bits(n2) | (f32_to_bf16_bits(n3) << 16); \
      *(uint2*)&alds[WB][widx[I]] = wv; }

// Backward epilogue: gate m_{t+1}; masked: c_t = c_{t+1} * exp2((g_t-g_{t+1})*log2e - e).
#define EPI_TILE_B(I, ACCI, GB, WB) { \
      const f32x4 g4 = GB[I]; \
      const float n0 = MM ? ACCI[0] * exp2f(fmaf(g4[0], LOG2E, -ef)) : sOld[I][0] * exp2f(fmaf(g4[0] - gp[I][0], LOG2E, -ef)); \
      const float n1 = MM ? ACCI[1] * exp2f(fmaf(g4[1], LOG2E, -ef)) : sOld[I][1] * exp2f(fmaf(g4[1] - gp[I][1], LOG2E, -ef)); \
      const float n2 = MM ? ACCI[2] * exp2f(fmaf(g4[2], LOG2E, -ef)) : sOld[I][2] * exp2f(fmaf(g4[2] - gp[I][2], LOG2E, -ef)); \
      const float n3 = MM ? ACCI[3] * exp2f(fmaf(g4[3], LOG2E, -ef)) : sOld[I][3] * exp2f(fmaf(g4[3] - gp[I][3], LOG2E, -ef)); \
      gp[I] = g4; \
      sOld[I][0] = n0; sOld[I][1] = n1; sOld[I][2] = n2; sOld[I][3] = n3; \
      mxl = fmaxf(mxl, fmaxf(fmaxf(n0, n1), fmaxf(n2, n3))); \
      uint2 wv; \
      wv.x = f32_to_bf16_bits(n0) | (f32_to_bf16_bits(n1) << 16); \
      wv.y = f32_to_bf16_bits(n2) | (f32_to_bf16_bits(n3) << 16); \
      *(uint2*)&alds[WB][widx[I]] = wv; }

// One forward step. Double-buffered alpha -> ONE barrier/step. Renorm max
// measured at t%4==3, applied at next t%4==0 (e from maxw, esum += e).
#define STEPF(T, RB, WB, GB, MR, APPLY, MEAS) { \
    MFMA_ALL(RB) \
    float ef = 0.f, sc = 1.0f; \
    if (APPLY) { \
      const f32x4 mx4 = *(const f32x4*)&maxw[p][0]; \
      const float mx = fmaxf(fmaxf(mx4[0], mx4[1]), fmaxf(mx4[2], mx4[3])); \
      const int e = (int)((__float_as_uint(mx) >> 23) & 0xFF) - 127; \
      esum += e; ef = (float)e; \
      sc = __uint_as_float((unsigned int)(127 - e) << 23); \
    } \
    const int MM = MR; \
    float mxl = -3.0e38f; \
    EPI_TILE_F(0, acc0, GB, WB) EPI_TILE_F(1, acc1, GB, WB) \
    EPI_TILE_F(2, acc2, GB, WB) EPI_TILE_F(3, acc3, GB, WB) \
    _Pragma("unroll") \
    for (int i2 = 0; i2 < 4; ++i2) GB[i2] = *(const f32x4*)(lgp + ((T) + 2) * NTAGS + 16 * i2); \
    MR = mkp[(T) + 2]; \
    if (MEAS) { \
      float v = mxl; v = fmaxf(v, __shfl_xor(v, 16)); v = fmaxf(v, __shfl_xor(v, 32)); \
      if (q == 0) maxw[p][wid] = v; \
    } \
    __syncthreads(); }

#define STEPB(T, RB, WB, GB, MR, APPLY, MEAS) { \
    MFMA_ALL(RB) \
    float ef = 0.f; \
    if (APPLY) { \
      const f32x4 mx4 = *(const f32x4*)&maxw[p][0]; \
      const float mx = fmaxf(fmaxf(mx4[0], mx4[1]), fmaxf(mx4[2], mx4[3])); \
      const int e = (int)((__float_as_uint(mx) >> 23) & 0xFF) - 127; \
      esum += e; ef = (float)e; \
    } \
    const int MM = MR; \
    float mxl = -3.0e38f; \
    EPI_TILE_B(0, acc0, GB, WB) EPI_TILE_B(1, acc1, GB, WB) \
    EPI_TILE_B(2, acc2, GB, WB) EPI_TILE_B(3, acc3, GB, WB) \
    _Pragma("unroll") \
    for (int i2 = 0; i2 < 4; ++i2) GB[i2] = *(const f32x4*)(lgp + ((T) - 2) * NTAGS + 16 * i2); \
    MR = mkp[(T) - 1]; \
    if (MEAS) { \
      float v = mxl; v = fmaxf(v, __shfl_xor(v, 16)); v = fmaxf(v, __shfl_xor(v, 32)); \
      if (q == 0) maxw[p][wid] = v; \
    } \
    __syncthreads(); }

// Pass 1: 8 blocks x 256 threads. Blocks 0-3: forward, 16 batches each,
// alpha_0 -> alpha_255. Blocks 4-7: backward, c_511 -> c_256 -> b_255.
__global__ __launch_bounds__(NTHREADS, 1)
void crf_halves(const float* __restrict__ logits,
                const int*   __restrict__ mask,
                const float* __restrict__ trans,
                float* __restrict__ wsA, float* __restrict__ wsB,
                int* __restrict__ wseF, int* __restrict__ wseB)
{
  const int bid  = blockIdx.x;
  const int bwd  = bid >> 2;
  const int b0   = (bid & 3) * MB;
  const int tid  = threadIdx.x;
  const int wid  = tid >> 6;        // wave 0..3 -> tag' range [64*wid, +64)
  const int lane = tid & 63;
  const int p    = lane & 15;       // batch column (mfma N / C-col)
  const int q    = lane >> 4;       // k-group (mfma A/B row-group)

  __shared__ __align__(16) short alds[2][NTAGS * MB];  // alpha bf16, [p][tag] ^ swz, dbuf
  __shared__ __align__(16) float maxw[16][4];          // per-batch per-wave renorm maxes

  const float* lgp = logits + (size_t)(b0 + p) * SEQ * NTAGS + 64 * wid + 4 * q;
  const int*   mkp = mask + (b0 + p) * SEQ;

  // LDS short-index helpers (XOR swizzle ^((p&7)<<3) shorts = ^((p&7)<<4) bytes:
  // keeps b128 reads conflict-light; write b64 and read b128 use the same XOR).
  int bidxs[8], widx[4];
#pragma unroll
  for (int c = 0; c < 8; ++c) bidxs[c] = (p * NTAGS + 32 * c + 8 * q) ^ ((p & 7) << 3);
#pragma unroll
  for (int i = 0; i < 4; ++i) widx[i] = (p * NTAGS + 64 * wid + 16 * i + 4 * q) ^ ((p & 7) << 3);

  // ---- E fragments in registers (constant across steps; 128 VGPRs) ----
  // fwd: A[m=tag',k=tag] = E^T = exp(trans[tag, tag']); bwd: exp(trans[tag', tag]).
  short8 aF[4][8];
#pragma unroll
  for (int i = 0; i < 4; ++i) {
    const int m = 64 * wid + 16 * i + p;   // A-row for this lane
#pragma unroll
    for (int c = 0; c < 8; ++c) {
      short8 w;
#pragma unroll
      for (int j = 0; j < 8; ++j) {
        const int tag = 32 * c + 8 * q + j;
        const float tv = bwd ? trans[m * NTAGS + tag] : trans[tag * NTAGS + m];
        w[j] = (short)f32_to_bf16_bits(exp2f(tv * LOG2E));
      }
      aF[i][c] = w;
    }
  }

  f32x4 sOld[4];            // alpha/c values this lane owns (4 tiles x 4 rows)
  f32x4 gE[4], gO[4], gp[4];
  int mE = 1, mO = 1;
  int esum = 0;

  if (!bwd) {
    // ---------------- forward: alpha_0 -> alpha_255 ----------------
#pragma unroll
    for (int i = 0; i < 4; ++i) {
      const f32x4 g0 = *(const f32x4*)(lgp + 16 * i);
      f32x4 a;
#pragma unroll
      for (int r = 0; r < 4; ++r) a[r] = exp2f(g0[r] * LOG2E);
      sOld[i] = a;
      uint2 wv;
      wv.x = f32_to_bf16_bits(a[0]) | (f32_to_bf16_bits(a[1]) << 16);
      wv.y = f32_to_bf16_bits(a[2]) | (f32_to_bf16_bits(a[3]) << 16);
      *(uint2*)&alds[0][widx[i]] = wv;
    }
#pragma unroll
    for (int i = 0; i < 4; ++i) {
      gO[i] = *(const f32x4*)(lgp + 1 * NTAGS + 16 * i);
      gE[i] = *(const f32x4*)(lgp + 2 * NTAGS + 16 * i);
    }
    mO = mkp[1]; mE = mkp[2];
    __syncthreads();

    STEPF(1, 0, 1, gO, mO, 0, 0)
    STEPF(2, 1, 0, gE, mE, 0, 0)
    STEPF(3, 0, 1, gO, mO, 0, 1)
#pragma unroll 1
    for (int tb = 4; tb <= 248; tb += 4) {
      STEPF(tb + 0, 1, 0, gE, mE, 1, 0)
      STEPF(tb + 1, 0, 1, gO, mO, 0, 0)
      STEPF(tb + 2, 1, 0, gE, mE, 0, 0)
      STEPF(tb + 3, 0, 1, gO, mO, 0, 1)
    }
    STEPF(252, 1, 0, gE, mE, 1, 0)
    STEPF(253, 0, 1, gO, mO, 0, 0)
    STEPF(254, 1, 0, gE, mE, 0, 0)

    // final step t=255: no renorm, no measure; write f32 alpha_255 to workspace
    {
      MFMA_ALL(0)
      const int MM = mO;    // mk[255]
      float* wp = wsA + (size_t)(b0 + p) * NTAGS + 64 * wid + 4 * q;
#pragma unroll
      for (int i = 0; i < 4; ++i) {
        const f32x4 g4 = gO[i];   // g_255
        f32x4 o;
        const f32x4 ac = (i == 0) ? acc0 : (i == 1) ? acc1 : (i == 2) ? acc2 : acc3;
#pragma unroll
        for (int r = 0; r < 4; ++r)
          o[r] = MM ? ac[r] * exp2f(g4[r] * LOG2E) : sOld[i][r];
        *(f32x4*)(wp + 16 * i) = o;
      }
    }
    if (tid < 16) wseF[b0 + tid] = esum;
  } else {
    // ---------------- backward: c_511 -> c_256 -> b_255 ----------------
#pragma unroll
    for (int i = 0; i < 4; ++i) {
      const f32x4 g5 = *(const f32x4*)(lgp + (SEQ - 1) * NTAGS + 16 * i);
      f32x4 a;
#pragma unroll
      for (int r = 0; r < 4; ++r) a[r] = exp2f(g5[r] * LOG2E);
      sOld[i] = a; gp[i] = g5;
      uint2 wv;
      wv.x = f32_to_bf16_bits(a[0]) | (f32_to_bf16_bits(a[1]) << 16);
      wv.y = f32_to_bf16_bits(a[2]) | (f32_to_bf16_bits(a[3]) << 16);
      *(uint2*)&alds[0][widx[i]] = wv;
    }
#pragma unroll
    for (int i = 0; i < 4; ++i) {
      gE[i] = *(const f32x4*)(lgp + 510 * NTAGS + 16 * i);
      gO[i] = *(const f32x4*)(lgp + 509 * NTAGS + 16 * i);
    }
    mE = mkp[511];   // gate for t=510 is m_{511}
    mO = mkp[510];   // gate for t=509 is m_{510}
    __syncthreads();

    STEPB(510, 0, 1, gE, mE, 0, 0)
    STEPB(509, 1, 0, gO, mO, 0, 0)
    STEPB(508, 0, 1, gE, mE, 0, 1)
#pragma unroll 1
    for (int tb = 507; tb >= 263; tb -= 4) {
      STEPB(tb - 0, 1, 0, gO, mO, 1, 0)
      STEPB(tb - 1, 0, 1, gE, mE, 0, 0)
      STEPB(tb - 2, 1, 0, gO, mO, 0, 0)
      STEPB(tb - 3, 0, 1, gE, mE, 0, 1)
    }
    STEPB(259, 1, 0, gO, mO, 1, 0)
    STEPB(258, 0, 1, gE, mE, 0, 0)
    STEPB(257, 1, 0, gO, mO, 0, 0)
    STEPB(256, 0, 1, gE, mE, 0, 0)   // full step; writes c_256 into buf 1

    // bare matvec b_255 = E * c_256 (no e^g), store f32
    {
      MFMA_ALL(1)
      float* wp = wsB + (size_t)(b0 + p) * NTAGS + 64 * wid + 4 * q;
      *(f32x4*)(wp + 0)  = acc0;
      *(f32x4*)(wp + 16) = acc1;
      *(f32x4*)(wp + 32) = acc2;
      *(f32x4*)(wp + 48) = acc3;
    }
    if (tid < 16) wseB[b0 + tid] = esum;
  }
}

// Pass 2 (stream-ordered): numerator + den = log(sum a_255 . b_255) + (Ef+Eb)*ln2
__global__ __launch_bounds__(256)
void crf_combine(const float* __restrict__ logits,
                 const int*   __restrict__ tags,
                 const int*   __restrict__ mask,
                 const float* __restrict__ trans,
                 const float* __restrict__ wsA,
                 const float* __restrict__ wsB,
                 const int*   __restrict__ wseF,
                 const int*   __restrict__ wseB,
                 float* __restrict__ out)
{
  const int b    = blockIdx.x;
  const int tid  = threadIdx.x;
  const int lane = tid & 63;
  const int wid  = tid >> 6;   // 0..3

  __shared__ float rn[4], rm[4], rp[4];

  const float LN2 = 0.6931471805599453f;
  const float* lg = logits + (size_t)b * SEQ * NTAGS;
  const int*   tg = tags + b * SEQ;
  const int*   mk = mask + b * SEQ;

  float numer = 0.f, msum = 0.f;
  for (int t = tid; t < SEQ; t += 256) {
    int   tag_t = tg[t];
    float m_t   = (float)mk[t];
    msum += m_t;
    if (t < SEQ - 1) {
      numer += lg[t * NTAGS + tag_t] * m_t;
      numer += trans[tag_t * NTAGS + tg[t + 1]] * (float)mk[t + 1];
    }
  }
  numer = wave_sum(numer);
  msum  = wave_sum(msum);
  if (lane == 0) { rn[wid] = numer; rm[wid] = msum; }

  float pprod = wsA[b * NTAGS + tid] * wsB[b * NTAGS + tid];
  pprod = wave_sum(pprod);
  if (lane == 0) rp[wid] = pprod;
  __syncthreads();

  if (tid == 0) {
    const float numer_tot = (rn[0] + rn[1]) + (rn[2] + rn[3]);
    const float msum_tot  = (rm[0] + rm[1]) + (rm[2] + rm[3]);
    const float psum      = (rp[0] + rp[1]) + (rp[2] + rp[3]);
    const float log_den   = logf(psum) + (float)(wseF[b] + wseB[b]) * LN2;
    int last_idx = (int)msum_tot - 1;
    if (last_idx < 0) last_idx = 0;
    const int last_tag = tg[last_idx];
    const float score = numer_tot + lg[(SEQ - 1) * NTAGS + last_tag] * (float)mk[SEQ - 1];
    atomicAdd(out, score - log_den);
  }
}

extern "C" void kernel_launch(void* const* d_in, const int* in_sizes, int n_in,
                              void* d_out, int out_size, void* d_ws, size_t ws_size,
                              hipStream_t stream) {
  const float* logits = (const float*)d_in[0];
  const int*   tags   = (const int*)d_in[1];
  const int*   mask   = (const int*)d_in[2];
  const float* trans  = (const float*)d_in[3];
  float* out = (float*)d_out;

  float* ws   = (float*)d_ws;
  float* wsA  = ws;                               // [64][256] alpha_255 * 2^-Ef
  float* wsB  = ws + BATCH * NTAGS;               // [64][256] b_255    * 2^-Eb
  int*   wseF = (int*)(ws + 2 * BATCH * NTAGS);   // [64]
  int*   wseB = wseF + BATCH;                     // [64]

  hipMemsetAsync(out, 0, sizeof(float), stream);  // harness poisons d_out
  crf_halves<<<dim3(8), dim3(NTHREADS), 0, stream>>>(logits, mask, trans, wsA, wsB, wseF, wseB);
  crf_combine<<<dim3(BATCH), dim3(256), 0, stream>>>(logits, tags, mask, trans, wsA, wsB, wseF, wseB, out);
}

// Round 4
// 285.952 us; speedup vs baseline: 1.2870x; 1.2870x over previous
//
#include <hip/hip_runtime.h>
#include <stdint.h>

#define NTAGS 256
#define BATCH 64
#define SEQ   512
#define MB    16          // batches per workgroup (the mfma N dimension)
#define NTHREADS 256      // 4 waves; wave w owns tag' range [64w, 64w+64)

typedef __attribute__((ext_vector_type(8))) short short8;   // 8 bf16 (4 VGPRs)
typedef __attribute__((ext_vector_type(4))) float f32x4;

__device__ __forceinline__ unsigned int f32_to_bf16_bits(float f) {
  unsigned int u = __float_as_uint(f);
  return (u + 0x7FFFu + ((u >> 16) & 1u)) >> 16;
}
__device__ __forceinline__ float wave_sum(float v) {
#pragma unroll
  for (int o = 32; o; o >>= 1) v += __shfl_xor(v, o);
  return v;
}
__device__ __forceinline__ unsigned int pk_bf16(float lo, float hi) {
  unsigned int r;
  asm("v_cvt_pk_bf16_f32 %0, %1, %2" : "=v"(r) : "v"(lo), "v"(hi));
  return r;
}

#define LOG2E 1.4426950408889634f

// One mfma sweep: D[tag',batch] += E' * alpha, 8 K-chunks, 4 M-tiles (acc0..3).
#define MFMA_ALL(RB) \
    f32x4 acc0 = {0.f,0.f,0.f,0.f}, acc1 = {0.f,0.f,0.f,0.f}, \
          acc2 = {0.f,0.f,0.f,0.f}, acc3 = {0.f,0.f,0.f,0.f}; \
    _Pragma("unroll") \
    for (int c = 0; c < 8; ++c) { \
      const short8 bf = *(const short8*)&alds[RB][bidxs[c]]; \
      acc0 = __builtin_amdgcn_mfma_f32_16x16x32_bf16(aF[0][c], bf, acc0, 0, 0, 0); \
      acc1 = __builtin_amdgcn_mfma_f32_16x16x32_bf16(aF[1][c], bf, acc1, 0, 0, 0); \
      acc2 = __builtin_amdgcn_mfma_f32_16x16x32_bf16(aF[2][c], bf, acc2, 0, 0, 0); \
      acc3 = __builtin_amdgcn_mfma_f32_16x16x32_bf16(aF[3][c], bf, acc3, 0, 0, 0); \
    }

// Forward epilogue tile: C/D layout (m89): lane col=p, rows tag'=64w+16I+4q+r.
// n = (m ? dot*P : old) * 2^-e.  P prefetched bf16 (uint2 = 4 rows).
#define EPI_TILE_F(I, ACCI, PB, WB) { \
      const uint2 pw = PB[I]; \
      const float p0 = __uint_as_float(pw.x << 16); \
      const float p1 = __uint_as_float(pw.x & 0xFFFF0000u); \
      const float p2 = __uint_as_float(pw.y << 16); \
      const float p3 = __uint_as_float(pw.y & 0xFFFF0000u); \
      const float n0 = (MM ? ACCI[0] * p0 : sOld[I][0]) * sc; \
      const float n1 = (MM ? ACCI[1] * p1 : sOld[I][1]) * sc; \
      const float n2 = (MM ? ACCI[2] * p2 : sOld[I][2]) * sc; \
      const float n3 = (MM ? ACCI[3] * p3 : sOld[I][3]) * sc; \
      sOld[I][0] = n0; sOld[I][1] = n1; sOld[I][2] = n2; sOld[I][3] = n3; \
      mxl = fmaxf(mxl, fmaxf(fmaxf(n0, n1), fmaxf(n2, n3))); \
      uint2 wv; wv.x = pk_bf16(n0, n1); wv.y = pk_bf16(n2, n3); \
      *(uint2*)&alds[WB][widx[I]] = wv; }

// Backward epilogue tile: gate m_{t+1}; masked: c_t = c_{t+1} * P_t/P_{t+1} * 2^-e.
// fastm (wave-uniform, always true in bench) skips the division path.
#define EPI_TILE_B(I, ACCI, PB, WB) { \
      const uint2 pw = PB[I]; \
      const float p0 = __uint_as_float(pw.x << 16); \
      const float p1 = __uint_as_float(pw.x & 0xFFFF0000u); \
      const float p2 = __uint_as_float(pw.y << 16); \
      const float p3 = __uint_as_float(pw.y & 0xFFFF0000u); \
      float n0, n1, n2, n3; \
      if (fastm) { \
        n0 = ACCI[0] * p0 * sc; n1 = ACCI[1] * p1 * sc; \
        n2 = ACCI[2] * p2 * sc; n3 = ACCI[3] * p3 * sc; \
      } else { \
        const float q0 = __uint_as_float(gp[I].x << 16); \
        const float q1 = __uint_as_float(gp[I].x & 0xFFFF0000u); \
        const float q2 = __uint_as_float(gp[I].y << 16); \
        const float q3 = __uint_as_float(gp[I].y & 0xFFFF0000u); \
        n0 = (MM ? ACCI[0] * p0 : sOld[I][0] * (p0 / q0)) * sc; \
        n1 = (MM ? ACCI[1] * p1 : sOld[I][1] * (p1 / q1)) * sc; \
        n2 = (MM ? ACCI[2] * p2 : sOld[I][2] * (p2 / q2)) * sc; \
        n3 = (MM ? ACCI[3] * p3 : sOld[I][3] * (p3 / q3)) * sc; \
      } \
      gp[I] = pw; \
      sOld[I][0] = n0; sOld[I][1] = n1; sOld[I][2] = n2; sOld[I][3] = n3; \
      mxl = fmaxf(mxl, fmaxf(fmaxf(n0, n1), fmaxf(n2, n3))); \
      uint2 wv; wv.x = pk_bf16(n0, n1); wv.y = pk_bf16(n2, n3); \
      *(uint2*)&alds[WB][widx[I]] = wv; }

// One forward step. Double-buffered alpha -> ONE barrier/step. Renorm max
// measured at t%4==3, applied at next t%4==0 (e from maxw, esum += e).
#define STEPF(T, RB, WB, PB, MR, APPLY, MEAS) { \
    MFMA_ALL(RB) \
    float sc = 1.0f; \
    if (APPLY) { \
      const f32x4 mx4 = *(const f32x4*)&maxw[p][0]; \
      const float mx = fmaxf(fmaxf(mx4[0], mx4[1]), fmaxf(mx4[2], mx4[3])); \
      const int e = (int)((__float_as_uint(mx) >> 23) & 0xFF) - 127; \
      esum += e; \
      sc = __uint_as_float((unsigned int)(127 - e) << 23); \
    } \
    const int MM = MR; \
    float mxl = -3.0e38f; \
    EPI_TILE_F(0, acc0, PB, WB) EPI_TILE_F(1, acc1, PB, WB) \
    EPI_TILE_F(2, acc2, PB, WB) EPI_TILE_F(3, acc3, PB, WB) \
    { const int tp_ = ((T) + 2 < SEQ) ? ((T) + 2) : (SEQ - 1); \
      _Pragma("unroll") \
      for (int i2 = 0; i2 < 4; ++i2) PB[i2] = *(const uint2*)(Pp + tp_ * NTAGS + 16 * i2); \
      MR = mkp[tp_]; } \
    if (MEAS) { \
      float v = mxl; v = fmaxf(v, __shfl_xor(v, 16)); v = fmaxf(v, __shfl_xor(v, 32)); \
      if (q == 0) maxw[p][wid] = v; \
    } \
    __syncthreads(); }

#define STEPB(T, RB, WB, PB, MR, APPLY, MEAS) { \
    MFMA_ALL(RB) \
    float sc = 1.0f; \
    if (APPLY) { \
      const f32x4 mx4 = *(const f32x4*)&maxw[p][0]; \
      const float mx = fmaxf(fmaxf(mx4[0], mx4[1]), fmaxf(mx4[2], mx4[3])); \
      const int e = (int)((__float_as_uint(mx) >> 23) & 0xFF) - 127; \
      esum += e; \
      sc = __uint_as_float((unsigned int)(127 - e) << 23); \
    } \
    const int MM = MR; \
    const bool fastm = (bool)__all(MM != 0); \
    float mxl = -3.0e38f; \
    EPI_TILE_B(0, acc0, PB, WB) EPI_TILE_B(1, acc1, PB, WB) \
    EPI_TILE_B(2, acc2, PB, WB) EPI_TILE_B(3, acc3, PB, WB) \
    { const int tp_ = ((T) >= 2) ? ((T) - 2) : 0; \
      const int tm_ = ((T) >= 1) ? ((T) - 1) : 0; \
      _Pragma("unroll") \
      for (int i2 = 0; i2 < 4; ++i2) PB[i2] = *(const uint2*)(Pp + tp_ * NTAGS + 16 * i2); \
      MR = mkp[tm_]; } \
    if (MEAS) { \
      float v = mxl; v = fmaxf(v, __shfl_xor(v, 16)); v = fmaxf(v, __shfl_xor(v, 32)); \
      if (q == 0) maxw[p][wid] = v; \
    } \
    __syncthreads(); }

// Prep: P[b][t][k] = e^{logits} as bf16. Fully parallel, memory-bound (~10us).
__global__ __launch_bounds__(256)
void crf_prep(const float* __restrict__ lg, unsigned int* __restrict__ P)
{
  const size_t g = (size_t)blockIdx.x * 256 + threadIdx.x;   // 8 floats / thread
  const float4 a = ((const float4*)lg)[2 * g];
  const float4 b = ((const float4*)lg)[2 * g + 1];
  uint4 o;
  o.x = pk_bf16(exp2f(a.x * LOG2E), exp2f(a.y * LOG2E));
  o.y = pk_bf16(exp2f(a.z * LOG2E), exp2f(a.w * LOG2E));
  o.z = pk_bf16(exp2f(b.x * LOG2E), exp2f(b.y * LOG2E));
  o.w = pk_bf16(exp2f(b.z * LOG2E), exp2f(b.w * LOG2E));
  ((uint4*)P)[g] = o;
}

// Pass 1: 8 blocks x 256 threads. Blocks 0-3: forward alpha_0 -> alpha_255
// (16 batches each). Blocks 4-7: backward c_511 -> c_256 -> b_255.
__global__ __launch_bounds__(NTHREADS, 1)
void crf_halves(const unsigned short* __restrict__ P,
                const int*   __restrict__ mask,
                const float* __restrict__ trans,
                float* __restrict__ wsA, float* __restrict__ wsB,
                int* __restrict__ wseF, int* __restrict__ wseB)
{
  const int bid  = blockIdx.x;
  const int bwd  = bid >> 2;
  const int b0   = (bid & 3) * MB;
  const int tid  = threadIdx.x;
  const int wid  = tid >> 6;        // wave 0..3 -> tag' range [64*wid, +64)
  const int lane = tid & 63;
  const int p    = lane & 15;       // batch column (mfma N / C-col)
  const int q    = lane >> 4;       // k-group (mfma A/B row-group)

  __shared__ __align__(16) short alds[2][NTAGS * MB];  // alpha bf16, dbuf, XOR-swz
  __shared__ __align__(16) float maxw[16][4];          // per-batch per-wave maxes

  const unsigned short* Pp = P + (size_t)(b0 + p) * SEQ * NTAGS + 64 * wid + 4 * q;
  const int* mkp = mask + (b0 + p) * SEQ;

  int bidxs[8], widx[4];
#pragma unroll
  for (int c = 0; c < 8; ++c) bidxs[c] = (p * NTAGS + 32 * c + 8 * q) ^ ((p & 7) << 3);
#pragma unroll
  for (int i = 0; i < 4; ++i) widx[i] = (p * NTAGS + 64 * wid + 16 * i + 4 * q) ^ ((p & 7) << 3);

  // ---- E fragments in registers (constant across steps; 128 VGPRs) ----
  short8 aF[4][8];
#pragma unroll
  for (int i = 0; i < 4; ++i) {
    const int m = 64 * wid + 16 * i + p;   // A-row for this lane
#pragma unroll
    for (int c = 0; c < 8; ++c) {
      short8 w;
#pragma unroll
      for (int j = 0; j < 8; ++j) {
        const int tag = 32 * c + 8 * q + j;
        const float tv = bwd ? trans[m * NTAGS + tag] : trans[tag * NTAGS + m];
        w[j] = (short)f32_to_bf16_bits(exp2f(tv * LOG2E));
      }
      aF[i][c] = w;
    }
  }

  f32x4 sOld[4];
  uint2 pE[4], pO[4], gp[4];
  int mE = 1, mO = 1;
  int esum = 0;

  if (!bwd) {
    // ---------------- forward: alpha_0 -> alpha_255 ----------------
#pragma unroll
    for (int i = 0; i < 4; ++i) {
      const uint2 pw = *(const uint2*)(Pp + 16 * i);     // P[t=0]
      f32x4 a;
      a[0] = __uint_as_float(pw.x << 16); a[1] = __uint_as_float(pw.x & 0xFFFF0000u);
      a[2] = __uint_as_float(pw.y << 16); a[3] = __uint_as_float(pw.y & 0xFFFF0000u);
      sOld[i] = a;
      *(uint2*)&alds[0][widx[i]] = pw;                   // already bf16-packed
    }
#pragma unroll
    for (int i = 0; i < 4; ++i) {
      pO[i] = *(const uint2*)(Pp + 1 * NTAGS + 16 * i);
      pE[i] = *(const uint2*)(Pp + 2 * NTAGS + 16 * i);
    }
    mO = mkp[1]; mE = mkp[2];
    __syncthreads();

    STEPF(1, 0, 1, pO, mO, 0, 0)
    STEPF(2, 1, 0, pE, mE, 0, 0)
    STEPF(3, 0, 1, pO, mO, 0, 1)
#pragma unroll 1
    for (int tb = 4; tb <= 248; tb += 4) {
      STEPF(tb + 0, 1, 0, pE, mE, 1, 0)
      STEPF(tb + 1, 0, 1, pO, mO, 0, 0)
      STEPF(tb + 2, 1, 0, pE, mE, 0, 0)
      STEPF(tb + 3, 0, 1, pO, mO, 0, 1)
    }
    STEPF(252, 1, 0, pE, mE, 1, 0)
    STEPF(253, 0, 1, pO, mO, 0, 0)
    STEPF(254, 1, 0, pE, mE, 0, 0)

    // final step t=255: no renorm; write f32 alpha_255 to workspace
    {
      MFMA_ALL(0)
      const int MM = mO;    // mk[255]
      float* wp = wsA + (size_t)(b0 + p) * NTAGS + 64 * wid + 4 * q;
#pragma unroll
      for (int i = 0; i < 4; ++i) {
        const uint2 pw = pO[i];   // P[255]
        f32x4 pv;
        pv[0] = __uint_as_float(pw.x << 16); pv[1] = __uint_as_float(pw.x & 0xFFFF0000u);
        pv[2] = __uint_as_float(pw.y << 16); pv[3] = __uint_as_float(pw.y & 0xFFFF0000u);
        f32x4 o;
        const f32x4 ac = (i == 0) ? acc0 : (i == 1) ? acc1 : (i == 2) ? acc2 : acc3;
#pragma unroll
        for (int r = 0; r < 4; ++r)
          o[r] = MM ? ac[r] * pv[r] : sOld[i][r];
        *(f32x4*)(wp + 16 * i) = o;
      }
    }
    if (tid < 16) wseF[b0 + tid] = esum;
  } else {
    // ---------------- backward: c_511 -> c_256 -> b_255 ----------------
#pragma unroll
    for (int i = 0; i < 4; ++i) {
      const uint2 pw = *(const uint2*)(Pp + (SEQ - 1) * NTAGS + 16 * i);  // P[511]
      f32x4 a;
      a[0] = __uint_as_float(pw.x << 16); a[1] = __uint_as_float(pw.x & 0xFFFF0000u);
      a[2] = __uint_as_float(pw.y << 16); a[3] = __uint_as_float(pw.y & 0xFFFF0000u);
      sOld[i] = a; gp[i] = pw;
      *(uint2*)&alds[0][widx[i]] = pw;
    }
#pragma unroll
    for (int i = 0; i < 4; ++i) {
      pE[i] = *(const uint2*)(Pp + 510 * NTAGS + 16 * i);
      pO[i] = *(const uint2*)(Pp + 509 * NTAGS + 16 * i);
    }
    mE = mkp[511];   // gate for t=510 is m_{511}
    mO = mkp[510];   // gate for t=509 is m_{510}
    __syncthreads();

    STEPB(510, 0, 1, pE, mE, 0, 0)
    STEPB(509, 1, 0, pO, mO, 0, 0)
    STEPB(508, 0, 1, pE, mE, 0, 1)
#pragma unroll 1
    for (int tb = 507; tb >= 263; tb -= 4) {
      STEPB(tb - 0, 1, 0, pO, mO, 1, 0)
      STEPB(tb - 1, 0, 1, pE, mE, 0, 0)
      STEPB(tb - 2, 1, 0, pO, mO, 0, 0)
      STEPB(tb - 3, 0, 1, pE, mE, 0, 1)
    }
    STEPB(259, 1, 0, pO, mO, 1, 0)
    STEPB(258, 0, 1, pE, mE, 0, 0)
    STEPB(257, 1, 0, pO, mO, 0, 0)
    STEPB(256, 0, 1, pE, mE, 0, 0)   // writes c_256 into buf 1

    // bare matvec b_255 = E * c_256 (no e^g), store f32
    {
      MFMA_ALL(1)
      float* wp = wsB + (size_t)(b0 + p) * NTAGS + 64 * wid + 4 * q;
      *(f32x4*)(wp + 0)  = acc0;
      *(f32x4*)(wp + 16) = acc1;
      *(f32x4*)(wp + 32) = acc2;
      *(f32x4*)(wp + 48) = acc3;
    }
    if (tid < 16) wseB[b0 + tid] = esum;
  }
}

// Pass 2: numerator + den = log(sum a_255 . b_255) + (Ef+Eb)*ln2
__global__ __launch_bounds__(256)
void crf_combine(const float* __restrict__ logits,
                 const int*   __restrict__ tags,
                 const int*   __restrict__ mask,
                 const float* __restrict__ trans,
                 const float* __restrict__ wsA,
                 const float* __restrict__ wsB,
                 const int*   __restrict__ wseF,
                 const int*   __restrict__ wseB,
                 float* __restrict__ out)
{
  const int b    = blockIdx.x;
  const int tid  = threadIdx.x;
  const int lane = tid & 63;
  const int wid  = tid >> 6;   // 0..3

  __shared__ float rn[4], rm[4], rp[4];

  const float LN2 = 0.6931471805599453f;
  const float* lg = logits + (size_t)b * SEQ * NTAGS;
  const int*   tg = tags + b * SEQ;
  const int*   mk = mask + b * SEQ;

  float numer = 0.f, msum = 0.f;
  for (int t = tid; t < SEQ; t += 256) {
    int   tag_t = tg[t];
    float m_t   = (float)mk[t];
    msum += m_t;
    if (t < SEQ - 1) {
      numer += lg[t * NTAGS + tag_t] * m_t;
      numer += trans[tag_t * NTAGS + tg[t + 1]] * (float)mk[t + 1];
    }
  }
  numer = wave_sum(numer);
  msum  = wave_sum(msum);
  if (lane == 0) { rn[wid] = numer; rm[wid] = msum; }

  float pprod = wsA[b * NTAGS + tid] * wsB[b * NTAGS + tid];
  pprod = wave_sum(pprod);
  if (lane == 0) rp[wid] = pprod;
  __syncthreads();

  if (tid == 0) {
    const float numer_tot = (rn[0] + rn[1]) + (rn[2] + rn[3]);
    const float msum_tot  = (rm[0] + rm[1]) + (rm[2] + rm[3]);
    const float psum      = (rp[0] + rp[1]) + (rp[2] + rp[3]);
    const float log_den   = logf(psum) + (float)(wseF[b] + wseB[b]) * LN2;
    int last_idx = (int)msum_tot - 1;
    if (last_idx < 0) last_idx = 0;
    const int last_tag = tg[last_idx];
    const float score = numer_tot + lg[(SEQ - 1) * NTAGS + last_tag] * (float)mk[SEQ - 1];
    atomicAdd(out, score - log_den);
  }
}

extern "C" void kernel_launch(void* const* d_in, const int* in_sizes, int n_in,
                              void* d_out, int out_size, void* d_ws, size_t ws_size,
                              hipStream_t stream) {
  const float* logits = (const float*)d_in[0];
  const int*   tags   = (const int*)d_in[1];
  const int*   mask   = (const int*)d_in[2];
  const float* trans  = (const float*)d_in[3];
  float* out = (float*)d_out;

  // workspace: P (16.78 MB bf16 e^logits) + boundary vectors + esums (~16.9 MB)
  unsigned short* P = (unsigned short*)d_ws;
  float* wsA  = (float*)((char*)d_ws + (size_t)BATCH * SEQ * NTAGS * 2);
  float* wsB  = wsA + BATCH * NTAGS;
  int*   wseF = (int*)(wsB + BATCH * NTAGS);
  int*   wseB = wseF + BATCH;

  hipMemsetAsync(out, 0, sizeof(float), stream);  // harness poisons d_out
  crf_prep<<<dim3(BATCH * SEQ * NTAGS / (256 * 8)), dim3(256), 0, stream>>>(logits, (unsigned int*)P);
  crf_halves<<<dim3(8), dim3(NTHREADS), 0, stream>>>(P, mask, trans, wsA, wsB, wseF, wseB);
  crf_combine<<<dim3(BATCH), dim3(256), 0, stream>>>(logits, tags, mask, trans, wsA, wsB, wseF, wseB, out);
}